// Round 4
// baseline (354.840 us; speedup 1.0000x reference)
//
#include <hip/hip_runtime.h>
#include <hip/hip_bf16.h>
#include <math.h>

#define LDIM 4096
#define NROWS 8192
#define NOUT 512

static const float SQRT_HALF_F = 0.70710678118654752440f;

typedef __attribute__((ext_vector_type(8))) short short8;
typedef __attribute__((ext_vector_type(4))) float f32x4;
typedef __attribute__((ext_vector_type(8))) unsigned short u16x8;
typedef __attribute__((ext_vector_type(4))) unsigned short u16x4;
typedef __attribute__((ext_vector_type(2))) unsigned short u16x2;

// ws layout
#define AM_OFF   0ull                         // bf16 masked A: 8192*4096*2 = 67108864
#define WT_OFF   67108864ull                  // bf16 Wt (N x K): 512*4096*2 = 4194304
#define PART_OFF (WT_OFF + 4194304ull)        // double[8192*2] partials
#define THR_OFF  (PART_OFF + 131072ull)       // float[1]

__device__ inline unsigned short f2bf(float f) {
  union { float f; unsigned u; } v; v.f = f;
  unsigned r = (v.u + 0x7fffu + ((v.u >> 16) & 1u)) >> 16;
  return (unsigned short)r;
}

__device__ inline unsigned short mcvt(float f, float thr) {
  return f2bf((fabsf(f) > thr) ? f : 0.0f);
}

__device__ inline void async16(void* l, const void* g) {
  __builtin_amdgcn_global_load_lds((const __attribute__((address_space(1))) void*)g,
                                   (__attribute__((address_space(3))) void*)l, 16, 0, 0);
}

// ---------------- Kernel 1: Haar stats (blocks 0..8191) + W convert (tail) ----
__global__ __launch_bounds__(256) void haar1_kernel(const float* __restrict__ x,
                                                    double* __restrict__ partials,
                                                    const float* __restrict__ W,
                                                    unsigned short* __restrict__ Wt) {
  if (blockIdx.x >= NROWS) {
    // ---- fused wcvt: W (K x N fp32) -> Wt (N x K bf16) ----
    __shared__ float tile[32][33];
    const int wb = blockIdx.x - NROWS;
    const int bx = wb & 15;        // n tile (16)
    const int by = wb >> 4;        // k tile (128)
    const int tx = threadIdx.x & 31, ty = threadIdx.x >> 5;
#pragma unroll
    for (int j = 0; j < 4; ++j)
      tile[ty + j * 8][tx] = W[(size_t)(by * 32 + ty + j * 8) * NOUT + bx * 32 + tx];
    __syncthreads();
#pragma unroll
    for (int j = 0; j < 4; ++j)
      Wt[(size_t)(bx * 32 + ty + j * 8) * LDIM + by * 32 + tx] = f2bf(tile[tx][ty + j * 8]);
    return;
  }

  __shared__ double red[8];
  const int row = blockIdx.x;
  const int t = threadIdx.x;
  const float S = SQRT_HALF_F;

  const float4* xr = (const float4*)(x + (size_t)row * LDIM) + 4 * t;
  float v[16];
#pragma unroll
  for (int k = 0; k < 4; ++k) {
    float4 q = xr[k];
    v[4 * k] = q.x; v[4 * k + 1] = q.y; v[4 * k + 2] = q.z; v[4 * k + 3] = q.w;
  }

  double sa = 0.0, sq = 0.0;
  float a1[8], a2[4], a3[2], a4;
#pragma unroll
  for (int j = 0; j < 8; ++j) {
    float d = (v[2 * j] - v[2 * j + 1]) * S;
    a1[j] = (v[2 * j] + v[2 * j + 1]) * S;
    sa += (double)fabsf(d); sq += (double)d * (double)d;
  }
#pragma unroll
  for (int j = 0; j < 4; ++j) {
    float d = (a1[2 * j] - a1[2 * j + 1]) * S;
    a2[j] = (a1[2 * j] + a1[2 * j + 1]) * S;
    sa += (double)fabsf(d); sq += (double)d * (double)d;
  }
#pragma unroll
  for (int j = 0; j < 2; ++j) {
    float d = (a2[2 * j] - a2[2 * j + 1]) * S;
    a3[j] = (a2[2 * j] + a2[2 * j + 1]) * S;
    sa += (double)fabsf(d); sq += (double)d * (double)d;
  }
  {
    float d = (a3[0] - a3[1]) * S;
    a4 = (a3[0] + a3[1]) * S;
    sa += (double)fabsf(d); sq += (double)d * (double)d;
  }
  {
    float other = __shfl_xor(a4, 1, 64);
    if ((t & 1) == 0) {
      float d = (a4 - other) * S, ap = (a4 + other) * S;
      sa += (double)fabsf(d) + (double)fabsf(ap);
      sq += (double)d * (double)d + (double)ap * (double)ap;
    }
  }

  const int lane = t & 63, wid = t >> 6;
#pragma unroll
  for (int off = 32; off > 0; off >>= 1) {
    sa += __shfl_down(sa, off, 64);
    sq += __shfl_down(sq, off, 64);
  }
  if (lane == 0) { red[wid] = sa; red[4 + wid] = sq; }
  __syncthreads();
  if (t == 0) {
    partials[2 * (size_t)row + 0] = red[0] + red[1] + red[2] + red[3];
    partials[2 * (size_t)row + 1] = red[4] + red[5] + red[6] + red[7];
  }
}

// ---------------- Kernel 2: reduce partials -> threshold ----------------
__global__ __launch_bounds__(1024) void thr_kernel(const double* __restrict__ partials,
                                                   float* __restrict__ thr) {
  __shared__ double red[32];
  const int tid = threadIdx.x;
  double sa = 0.0, sq = 0.0;
#pragma unroll
  for (int k = 0; k < NROWS / 1024; ++k) {
    int i = tid + k * 1024;
    sa += partials[2 * i + 0];
    sq += partials[2 * i + 1];
  }
  const int lane = tid & 63, wid = tid >> 6;
#pragma unroll
  for (int off = 32; off > 0; off >>= 1) {
    sa += __shfl_down(sa, off, 64);
    sq += __shfl_down(sq, off, 64);
  }
  if (lane == 0) { red[wid] = sa; red[16 + wid] = sq; }
  __syncthreads();
  if (tid == 0) {
    double s = 0.0, q = 0.0;
#pragma unroll
    for (int i = 0; i < 16; ++i) { s += red[i]; q += red[16 + i]; }
    const double n = (double)NROWS * (double)LDIM;
    double mean = s / n;
    double var = (q - s * s / n) / (n - 1.0);
    *thr = (float)(mean + sqrt(var));
  }
}

// ---------------- Kernel 3: Haar recompute + mask + bf16 write ----------------
__global__ __launch_bounds__(256) void haar2_kernel(const float* __restrict__ x,
                                                    const float* __restrict__ thrp,
                                                    unsigned short* __restrict__ Am) {
  const float thr = *thrp;
  const int row = blockIdx.x;
  const int t = threadIdx.x;
  const float S = SQRT_HALF_F;

  const float4* xr = (const float4*)(x + (size_t)row * LDIM) + 4 * t;
  float v[16];
#pragma unroll
  for (int k = 0; k < 4; ++k) {
    float4 q = xr[k];
    v[4 * k] = q.x; v[4 * k + 1] = q.y; v[4 * k + 2] = q.z; v[4 * k + 3] = q.w;
  }

  unsigned short* orow = Am + (size_t)row * LDIM;
  float a1[8], a2[4], a3[2], a4;

  u16x8 d1;
#pragma unroll
  for (int j = 0; j < 8; ++j) {
    float d = (v[2 * j] - v[2 * j + 1]) * S;
    a1[j] = (v[2 * j] + v[2 * j + 1]) * S;
    d1[j] = mcvt(d, thr);
  }
  *(u16x8*)(orow + 2048 + 8 * t) = d1;

  u16x4 d2;
#pragma unroll
  for (int j = 0; j < 4; ++j) {
    float d = (a1[2 * j] - a1[2 * j + 1]) * S;
    a2[j] = (a1[2 * j] + a1[2 * j + 1]) * S;
    d2[j] = mcvt(d, thr);
  }
  *(u16x4*)(orow + 1024 + 4 * t) = d2;

  u16x2 d3;
#pragma unroll
  for (int j = 0; j < 2; ++j) {
    float d = (a2[2 * j] - a2[2 * j + 1]) * S;
    a3[j] = (a2[2 * j] + a2[2 * j + 1]) * S;
    d3[j] = mcvt(d, thr);
  }
  *(u16x2*)(orow + 512 + 2 * t) = d3;

  {
    float d = (a3[0] - a3[1]) * S;
    a4 = (a3[0] + a3[1]) * S;
    orow[256 + t] = mcvt(d, thr);
  }
  {
    float other = __shfl_xor(a4, 1, 64);
    if ((t & 1) == 0) {
      float d = (a4 - other) * S, ap = (a4 + other) * S;
      orow[128 + t / 2] = mcvt(d, thr);
      orow[t / 2] = mcvt(ap, thr);
    }
  }
}

// ---------------- Kernel 4: bf16 MFMA GEMM + ReLU, 512 threads ----------------
// C[8192x512] = relu( Am @ Wt^T ). Round-8 = round-7 resubmit (infra failure,
// kernel never ran). Structure:
// Tile 128m x 64n, BK=64, 8 waves (wave tile 32x32), grid 512, 2 blocks/CU
// (round-2 showed 1 block/CU exposes the per-iter drain: +13 us).
// A: global_load_lds double-buffered, XOR-8 chunk swizzle via DMA source addr.
// B: DIRECT from global (L2-resident 4 MB Wt panel) into VGPR fragments --
// no LDS round-trip. Halves LDS-read wall (41 -> 20 us) at unchanged
// occupancy; B-load L2 latency (~200cy) hidden by 4 waves/SIMD TLP.
// vmcnt bookkeeping: B loads are compiler-visible (precise waits auto-
// inserted before MFMA); manual vmcnt(0)+s_barrier only guards the A dbuf.
// Brow pointers are named scalars (not a runtime-indexed array) per rule #20.
#define GEMM_COMPUTE(ASB, k0)                                                         \
  {                                                                                   \
    short8 af[2][2], bf[2][2];                                                        \
    _Pragma("unroll")                                                                 \
    for (int ks = 0; ks < 2; ++ks) {                                                  \
      bf[0][ks] = *(const short8*)(Brow0 + (k0) + ks * 32);                           \
      bf[1][ks] = *(const short8*)(Brow1 + (k0) + ks * 32);                           \
    }                                                                                 \
    _Pragma("unroll")                                                                 \
    for (int mi = 0; mi < 2; ++mi) {                                                  \
      const int arow = wm * 32 + mi * 16 + l15;                                       \
      _Pragma("unroll")                                                               \
      for (int ks = 0; ks < 2; ++ks)                                                  \
        af[mi][ks] = *(const short8*)&(ASB)[arow * 64 + ((ks * 4 + quad) ^ (arow & 7)) * 8]; \
    }                                                                                 \
    _Pragma("unroll")                                                                 \
    for (int ks = 0; ks < 2; ++ks)                                                    \
      _Pragma("unroll")                                                               \
      for (int mi = 0; mi < 2; ++mi)                                                  \
        _Pragma("unroll")                                                             \
        for (int ni = 0; ni < 2; ++ni)                                                \
          acc[mi][ni] = __builtin_amdgcn_mfma_f32_16x16x32_bf16(af[mi][ks], bf[ni][ks], \
                                                                acc[mi][ni], 0, 0, 0); \
  }

__global__ __launch_bounds__(512) void gemm_kernel(const unsigned short* __restrict__ Am,
                                                   const unsigned short* __restrict__ Wt,
                                                   float* __restrict__ out) {
  __shared__ __align__(16) unsigned short As[2][128 * 64];  // 2 x 16 KB (A only)

  const int tid = threadIdx.x;
  const int lane = tid & 63, w = tid >> 6;      // 8 waves
  const int quad = lane >> 4, l15 = lane & 15;
  const int wm = w >> 1, wn = w & 1;            // 4m x 2n wave grid

  const int id = blockIdx.x;                    // grid 512
  const int xcd = id & 7, slot = id >> 3;
  const int nblk = slot & 7;
  const int mblk = (slot >> 3) * 8 + xcd;
  const int n0 = nblk * 64, m0 = mblk * 128;

  f32x4 acc[2][2] = {};

  const int rl = lane >> 3;            // row within an 8-row DMA group
  const int cg = (lane & 7) ^ rl;      // XOR-swizzled source chunk index
  const unsigned short* AgBase = Am + (size_t)(m0 + rl) * LDIM + cg * 8;

  // B fragment row pointers: row = n0 + wn*32 + ni*16 + l15, chunk base quad*8.
  // Per K-step k0, frag (ni,ks) = 16 B at Brow{ni} + k0 + ks*32.
  const unsigned short* Brow0 = Wt + (size_t)(n0 + wn * 32 + 0 * 16 + l15) * LDIM + quad * 8;
  const unsigned short* Brow1 = Wt + (size_t)(n0 + wn * 32 + 1 * 16 + l15) * LDIM + quad * 8;

  // per-wave STAGE of one A K-tile into buffer `buf` (2 async16 per wave)
#define GEMM_STAGE(buf, k0)                                                            \
  {                                                                                    \
    _Pragma("unroll")                                                                  \
    for (int j = 0; j < 2; ++j)                                                        \
      async16(&As[buf][(w * 2 + j) * 512], AgBase + (size_t)((w * 2 + j) * 8) * LDIM + (k0)); \
  }

  // prologue: stage tile 0, wait, barrier
  GEMM_STAGE(0, 0);
  asm volatile("s_waitcnt vmcnt(0)" ::: "memory");
  __builtin_amdgcn_s_barrier();
  __builtin_amdgcn_sched_barrier(0);

  int cur = 0;
  for (int t = 0; t < (LDIM / 64) - 1; ++t) {
    GEMM_STAGE(cur ^ 1, (t + 1) * 64);       // A prefetch flies over compute
    GEMM_COMPUTE(As[cur], t * 64);           // B direct loads + A ds_reads + MFMA
    asm volatile("s_waitcnt vmcnt(0)" ::: "memory");
    __builtin_amdgcn_s_barrier();
    __builtin_amdgcn_sched_barrier(0);
    cur ^= 1;
  }
  GEMM_COMPUTE(As[cur], (LDIM - 64));        // epilogue tile, no prefetch

  // C/D layout: col = lane&15, row = quad*4 + reg (verified rounds 1-4)
#pragma unroll
  for (int mi = 0; mi < 2; ++mi) {
#pragma unroll
    for (int ni = 0; ni < 2; ++ni) {
      const int r0 = m0 + wm * 32 + mi * 16 + quad * 4;
      const int c = n0 + wn * 32 + ni * 16 + l15;
#pragma unroll
      for (int r = 0; r < 4; ++r)
        out[(size_t)(r0 + r) * NOUT + c] = fmaxf(acc[mi][ni][r], 0.0f);
    }
  }
}

extern "C" void kernel_launch(void* const* d_in, const int* in_sizes, int n_in,
                              void* d_out, int out_size, void* d_ws, size_t ws_size,
                              hipStream_t stream) {
  const float* x = (const float*)d_in[0];
  const float* W = (const float*)d_in[1];
  float* out = (float*)d_out;

  char* ws = (char*)d_ws;
  unsigned short* Am = (unsigned short*)(ws + AM_OFF);
  unsigned short* Wt = (unsigned short*)(ws + WT_OFF);
  double* partials = (double*)(ws + PART_OFF);
  float* thr = (float*)(ws + THR_OFF);

  haar1_kernel<<<NROWS + 2048, 256, 0, stream>>>(x, partials, W, Wt);
  thr_kernel<<<1, 1024, 0, stream>>>(partials, thr);
  haar2_kernel<<<NROWS, 256, 0, stream>>>(x, thr, Am);
  gemm_kernel<<<512, 512, 0, stream>>>(Am, Wt, out);
}

// Round 5
// 278.442 us; speedup vs baseline: 1.2744x; 1.2744x over previous
//
#include <hip/hip_runtime.h>
#include <hip/hip_bf16.h>
#include <math.h>

#define LDIM 4096
#define NROWS 8192
#define NOUT 512

static const float SQRT_HALF_F = 0.70710678118654752440f;

typedef __attribute__((ext_vector_type(8))) short short8;
typedef __attribute__((ext_vector_type(4))) float f32x4;
typedef __attribute__((ext_vector_type(8))) unsigned short u16x8;
typedef __attribute__((ext_vector_type(4))) unsigned short u16x4;
typedef __attribute__((ext_vector_type(2))) unsigned short u16x2;

// ws layout
#define AM_OFF   0ull                         // bf16 masked A: 8192*4096*2 = 67108864
#define WT_OFF   67108864ull                  // bf16 Wt (N x K): 512*4096*2 = 4194304
#define PART_OFF (WT_OFF + 4194304ull)        // double[8192*2] partials
#define THR_OFF  (PART_OFF + 131072ull)       // float[1]

__device__ inline unsigned short f2bf(float f) {
  union { float f; unsigned u; } v; v.f = f;
  unsigned r = (v.u + 0x7fffu + ((v.u >> 16) & 1u)) >> 16;
  return (unsigned short)r;
}

__device__ inline unsigned short mcvt(float f, float thr) {
  return f2bf((fabsf(f) > thr) ? f : 0.0f);
}

__device__ inline void async16(void* l, const void* g) {
  __builtin_amdgcn_global_load_lds((const __attribute__((address_space(1))) void*)g,
                                   (__attribute__((address_space(3))) void*)l, 16, 0, 0);
}

// ---------------- Kernel 1: Haar stats (blocks 0..8191) + W convert (tail) ----
__global__ __launch_bounds__(256) void haar1_kernel(const float* __restrict__ x,
                                                    double* __restrict__ partials,
                                                    const float* __restrict__ W,
                                                    unsigned short* __restrict__ Wt) {
  if (blockIdx.x >= NROWS) {
    // ---- fused wcvt: W (K x N fp32) -> Wt (N x K bf16) ----
    __shared__ float tile[32][33];
    const int wb = blockIdx.x - NROWS;
    const int bx = wb & 15;        // n tile (16)
    const int by = wb >> 4;        // k tile (128)
    const int tx = threadIdx.x & 31, ty = threadIdx.x >> 5;
#pragma unroll
    for (int j = 0; j < 4; ++j)
      tile[ty + j * 8][tx] = W[(size_t)(by * 32 + ty + j * 8) * NOUT + bx * 32 + tx];
    __syncthreads();
#pragma unroll
    for (int j = 0; j < 4; ++j)
      Wt[(size_t)(bx * 32 + ty + j * 8) * LDIM + by * 32 + tx] = f2bf(tile[tx][ty + j * 8]);
    return;
  }

  __shared__ double red[8];
  const int row = blockIdx.x;
  const int t = threadIdx.x;
  const float S = SQRT_HALF_F;

  const float4* xr = (const float4*)(x + (size_t)row * LDIM) + 4 * t;
  float v[16];
#pragma unroll
  for (int k = 0; k < 4; ++k) {
    float4 q = xr[k];
    v[4 * k] = q.x; v[4 * k + 1] = q.y; v[4 * k + 2] = q.z; v[4 * k + 3] = q.w;
  }

  double sa = 0.0, sq = 0.0;
  float a1[8], a2[4], a3[2], a4;
#pragma unroll
  for (int j = 0; j < 8; ++j) {
    float d = (v[2 * j] - v[2 * j + 1]) * S;
    a1[j] = (v[2 * j] + v[2 * j + 1]) * S;
    sa += (double)fabsf(d); sq += (double)d * (double)d;
  }
#pragma unroll
  for (int j = 0; j < 4; ++j) {
    float d = (a1[2 * j] - a1[2 * j + 1]) * S;
    a2[j] = (a1[2 * j] + a1[2 * j + 1]) * S;
    sa += (double)fabsf(d); sq += (double)d * (double)d;
  }
#pragma unroll
  for (int j = 0; j < 2; ++j) {
    float d = (a2[2 * j] - a2[2 * j + 1]) * S;
    a3[j] = (a2[2 * j] + a2[2 * j + 1]) * S;
    sa += (double)fabsf(d); sq += (double)d * (double)d;
  }
  {
    float d = (a3[0] - a3[1]) * S;
    a4 = (a3[0] + a3[1]) * S;
    sa += (double)fabsf(d); sq += (double)d * (double)d;
  }
  {
    float other = __shfl_xor(a4, 1, 64);
    if ((t & 1) == 0) {
      float d = (a4 - other) * S, ap = (a4 + other) * S;
      sa += (double)fabsf(d) + (double)fabsf(ap);
      sq += (double)d * (double)d + (double)ap * (double)ap;
    }
  }

  const int lane = t & 63, wid = t >> 6;
#pragma unroll
  for (int off = 32; off > 0; off >>= 1) {
    sa += __shfl_down(sa, off, 64);
    sq += __shfl_down(sq, off, 64);
  }
  if (lane == 0) { red[wid] = sa; red[4 + wid] = sq; }
  __syncthreads();
  if (t == 0) {
    partials[2 * (size_t)row + 0] = red[0] + red[1] + red[2] + red[3];
    partials[2 * (size_t)row + 1] = red[4] + red[5] + red[6] + red[7];
  }
}

// ---------------- Kernel 2: reduce partials -> threshold ----------------
__global__ __launch_bounds__(1024) void thr_kernel(const double* __restrict__ partials,
                                                   float* __restrict__ thr) {
  __shared__ double red[32];
  const int tid = threadIdx.x;
  double sa = 0.0, sq = 0.0;
#pragma unroll
  for (int k = 0; k < NROWS / 1024; ++k) {
    int i = tid + k * 1024;
    sa += partials[2 * i + 0];
    sq += partials[2 * i + 1];
  }
  const int lane = tid & 63, wid = tid >> 6;
#pragma unroll
  for (int off = 32; off > 0; off >>= 1) {
    sa += __shfl_down(sa, off, 64);
    sq += __shfl_down(sq, off, 64);
  }
  if (lane == 0) { red[wid] = sa; red[16 + wid] = sq; }
  __syncthreads();
  if (tid == 0) {
    double s = 0.0, q = 0.0;
#pragma unroll
    for (int i = 0; i < 16; ++i) { s += red[i]; q += red[16 + i]; }
    const double n = (double)NROWS * (double)LDIM;
    double mean = s / n;
    double var = (q - s * s / n) / (n - 1.0);
    *thr = (float)(mean + sqrt(var));
  }
}

// ---------------- Kernel 3: Haar recompute + mask + bf16 write ----------------
__global__ __launch_bounds__(256) void haar2_kernel(const float* __restrict__ x,
                                                    const float* __restrict__ thrp,
                                                    unsigned short* __restrict__ Am) {
  const float thr = *thrp;
  const int row = blockIdx.x;
  const int t = threadIdx.x;
  const float S = SQRT_HALF_F;

  const float4* xr = (const float4*)(x + (size_t)row * LDIM) + 4 * t;
  float v[16];
#pragma unroll
  for (int k = 0; k < 4; ++k) {
    float4 q = xr[k];
    v[4 * k] = q.x; v[4 * k + 1] = q.y; v[4 * k + 2] = q.z; v[4 * k + 3] = q.w;
  }

  unsigned short* orow = Am + (size_t)row * LDIM;
  float a1[8], a2[4], a3[2], a4;

  u16x8 d1;
#pragma unroll
  for (int j = 0; j < 8; ++j) {
    float d = (v[2 * j] - v[2 * j + 1]) * S;
    a1[j] = (v[2 * j] + v[2 * j + 1]) * S;
    d1[j] = mcvt(d, thr);
  }
  *(u16x8*)(orow + 2048 + 8 * t) = d1;

  u16x4 d2;
#pragma unroll
  for (int j = 0; j < 4; ++j) {
    float d = (a1[2 * j] - a1[2 * j + 1]) * S;
    a2[j] = (a1[2 * j] + a1[2 * j + 1]) * S;
    d2[j] = mcvt(d, thr);
  }
  *(u16x4*)(orow + 1024 + 4 * t) = d2;

  u16x2 d3;
#pragma unroll
  for (int j = 0; j < 2; ++j) {
    float d = (a2[2 * j] - a2[2 * j + 1]) * S;
    a3[j] = (a2[2 * j] + a2[2 * j + 1]) * S;
    d3[j] = mcvt(d, thr);
  }
  *(u16x2*)(orow + 512 + 2 * t) = d3;

  {
    float d = (a3[0] - a3[1]) * S;
    a4 = (a3[0] + a3[1]) * S;
    orow[256 + t] = mcvt(d, thr);
  }
  {
    float other = __shfl_xor(a4, 1, 64);
    if ((t & 1) == 0) {
      float d = (a4 - other) * S, ap = (a4 + other) * S;
      orow[128 + t / 2] = mcvt(d, thr);
      orow[t / 2] = mcvt(ap, thr);
    }
  }
}

// ---------------- Kernel 4: bf16 MFMA GEMM + ReLU, 256 threads ----------------
// C[8192x512] = relu( Am @ Wt^T ). Round-9 structure:
// Round-4 post-mortem: B direct-from-global = 16-line gather per load, fully
// latency-exposed (MfmaUtil 9%, gemm 141us). B goes back through LDS.
// Round-1 identity pinned that structure's gemm at ~53us ~= LDS-read wall
// (64 ds_read_b128/block/K-step, ratio 1 MFMA/read).
// This round: SAME 128m x 64n block tile (grid 512, 2 blocks/CU preserved —
// round-2 proved 1 block/CU fails), but 4 waves x wave-tile 32x64 (4m x 1n,
// 2x4 frags): 48 reads per 64 MFMA per block-step (ratio 1.33). LDS wall
// 41 -> ~31us. Staging volume/swizzle/dbuf identical; 6 async16 per wave.
// Risk: 8 waves/CU (2/SIMD) TLP; fallback = round-1 8-wave form.
#define GEMM_COMPUTE(ASB, BSB)                                                        \
  {                                                                                   \
    short8 af[2][2], bf[4][2];                                                        \
    _Pragma("unroll")                                                                 \
    for (int mi = 0; mi < 2; ++mi) {                                                  \
      const int arow = wm * 32 + mi * 16 + l15;                                       \
      _Pragma("unroll")                                                               \
      for (int ks = 0; ks < 2; ++ks)                                                  \
        af[mi][ks] = *(const short8*)&(ASB)[arow * 64 + ((ks * 4 + quad) ^ (arow & 7)) * 8]; \
    }                                                                                 \
    _Pragma("unroll")                                                                 \
    for (int ni = 0; ni < 4; ++ni) {                                                  \
      const int brow = ni * 16 + l15;                                                 \
      _Pragma("unroll")                                                               \
      for (int ks = 0; ks < 2; ++ks)                                                  \
        bf[ni][ks] = *(const short8*)&(BSB)[brow * 64 + ((ks * 4 + quad) ^ (brow & 7)) * 8]; \
    }                                                                                 \
    _Pragma("unroll")                                                                 \
    for (int ks = 0; ks < 2; ++ks)                                                    \
      _Pragma("unroll")                                                               \
      for (int mi = 0; mi < 2; ++mi)                                                  \
        _Pragma("unroll")                                                             \
        for (int ni = 0; ni < 4; ++ni)                                                \
          acc[mi][ni] = __builtin_amdgcn_mfma_f32_16x16x32_bf16(af[mi][ks], bf[ni][ks], \
                                                                acc[mi][ni], 0, 0, 0); \
  }

__global__ __launch_bounds__(256) void gemm_kernel(const unsigned short* __restrict__ Am,
                                                   const unsigned short* __restrict__ Wt,
                                                   float* __restrict__ out) {
  __shared__ __align__(16) unsigned short As[2][128 * 64];  // 2 x 16 KB
  __shared__ __align__(16) unsigned short Bs[2][64 * 64];   // 2 x  8 KB

  const int tid = threadIdx.x;
  const int lane = tid & 63, w = tid >> 6;      // 4 waves
  const int quad = lane >> 4, l15 = lane & 15;
  const int wm = w;                              // 4m x 1n wave grid, wave tile 32x64

  const int id = blockIdx.x;                    // grid 512
  const int xcd = id & 7, slot = id >> 3;
  const int nblk = slot & 7;
  const int mblk = (slot >> 3) * 8 + xcd;
  const int n0 = nblk * 64, m0 = mblk * 128;

  f32x4 acc[2][4] = {};

  const int rl = lane >> 3;            // row within an 8-row DMA group
  const int cg = (lane & 7) ^ rl;      // XOR-swizzled source chunk index
  const unsigned short* AgBase = Am + (size_t)(m0 + rl) * LDIM + cg * 8;
  const unsigned short* BgBase = Wt + (size_t)(n0 + rl) * LDIM + cg * 8;

  // per-wave STAGE: A 128 rows = 16 groups of 8 (4 per wave); B 64 rows =
  // 8 groups (2 per wave). 6 async16 per wave per tile.
#define GEMM_STAGE(buf, k0)                                                            \
  {                                                                                    \
    _Pragma("unroll")                                                                  \
    for (int j = 0; j < 4; ++j)                                                        \
      async16(&As[buf][(w * 4 + j) * 512], AgBase + (size_t)((w * 4 + j) * 8) * LDIM + (k0)); \
    _Pragma("unroll")                                                                  \
    for (int j = 0; j < 2; ++j)                                                        \
      async16(&Bs[buf][(w * 2 + j) * 512], BgBase + (size_t)((w * 2 + j) * 8) * LDIM + (k0)); \
  }

  // prologue: stage tile 0, wait, barrier
  GEMM_STAGE(0, 0);
  asm volatile("s_waitcnt vmcnt(0)" ::: "memory");
  __builtin_amdgcn_s_barrier();
  __builtin_amdgcn_sched_barrier(0);

  int cur = 0;
  for (int t = 0; t < (LDIM / 64) - 1; ++t) {
    GEMM_STAGE(cur ^ 1, (t + 1) * 64);   // next-tile prefetch flies over compute
    GEMM_COMPUTE(As[cur], Bs[cur]);
    asm volatile("s_waitcnt vmcnt(0)" ::: "memory");
    __builtin_amdgcn_s_barrier();
    __builtin_amdgcn_sched_barrier(0);
    cur ^= 1;
  }
  GEMM_COMPUTE(As[cur], Bs[cur]);        // epilogue tile, no prefetch

  // C/D layout: col = lane&15, row = quad*4 + reg (verified rounds 1-4)
#pragma unroll
  for (int mi = 0; mi < 2; ++mi) {
#pragma unroll
    for (int ni = 0; ni < 4; ++ni) {
      const int r0 = m0 + wm * 32 + mi * 16 + quad * 4;
      const int c = n0 + ni * 16 + l15;
#pragma unroll
      for (int r = 0; r < 4; ++r)
        out[(size_t)(r0 + r) * NOUT + c] = fmaxf(acc[mi][ni][r], 0.0f);
    }
  }
}

extern "C" void kernel_launch(void* const* d_in, const int* in_sizes, int n_in,
                              void* d_out, int out_size, void* d_ws, size_t ws_size,
                              hipStream_t stream) {
  const float* x = (const float*)d_in[0];
  const float* W = (const float*)d_in[1];
  float* out = (float*)d_out;

  char* ws = (char*)d_ws;
  unsigned short* Am = (unsigned short*)(ws + AM_OFF);
  unsigned short* Wt = (unsigned short*)(ws + WT_OFF);
  double* partials = (double*)(ws + PART_OFF);
  float* thr = (float*)(ws + THR_OFF);

  haar1_kernel<<<NROWS + 2048, 256, 0, stream>>>(x, partials, W, Wt);
  thr_kernel<<<1, 1024, 0, stream>>>(partials, thr);
  haar2_kernel<<<NROWS, 256, 0, stream>>>(x, thr, Am);
  gemm_kernel<<<512, 256, 0, stream>>>(Am, Wt, out);
}

// Round 6
// 270.095 us; speedup vs baseline: 1.3138x; 1.0309x over previous
//
#include <hip/hip_runtime.h>
#include <hip/hip_bf16.h>
#include <math.h>

#define LDIM 4096
#define NROWS 8192
#define NOUT 512

static const float SQRT_HALF_F = 0.70710678118654752440f;

typedef __attribute__((ext_vector_type(8))) short short8;
typedef __attribute__((ext_vector_type(4))) float f32x4;
typedef __attribute__((ext_vector_type(16))) float f32x16;
typedef __attribute__((ext_vector_type(8))) unsigned short u16x8;
typedef __attribute__((ext_vector_type(4))) unsigned short u16x4;
typedef __attribute__((ext_vector_type(2))) unsigned short u16x2;

// ws layout
#define AM_OFF   0ull                         // bf16 masked A: 8192*4096*2 = 67108864
#define WT_OFF   67108864ull                  // bf16 Wt (N x K): 512*4096*2 = 4194304
#define PART_OFF (WT_OFF + 4194304ull)        // double[8192*2] partials
#define THR_OFF  (PART_OFF + 131072ull)       // float[1]

__device__ inline unsigned short f2bf(float f) {
  union { float f; unsigned u; } v; v.f = f;
  unsigned r = (v.u + 0x7fffu + ((v.u >> 16) & 1u)) >> 16;
  return (unsigned short)r;
}

__device__ inline unsigned short mcvt(float f, float thr) {
  return f2bf((fabsf(f) > thr) ? f : 0.0f);
}

__device__ inline void async16(void* l, const void* g) {
  __builtin_amdgcn_global_load_lds((const __attribute__((address_space(1))) void*)g,
                                   (__attribute__((address_space(3))) void*)l, 16, 0, 0);
}

// ---------------- Kernel 1: Haar stats (blocks 0..8191) + W convert (tail) ----
__global__ __launch_bounds__(256) void haar1_kernel(const float* __restrict__ x,
                                                    double* __restrict__ partials,
                                                    const float* __restrict__ W,
                                                    unsigned short* __restrict__ Wt) {
  if (blockIdx.x >= NROWS) {
    // ---- fused wcvt: W (K x N fp32) -> Wt (N x K bf16) ----
    __shared__ float tile[32][33];
    const int wb = blockIdx.x - NROWS;
    const int bx = wb & 15;        // n tile (16)
    const int by = wb >> 4;        // k tile (128)
    const int tx = threadIdx.x & 31, ty = threadIdx.x >> 5;
#pragma unroll
    for (int j = 0; j < 4; ++j)
      tile[ty + j * 8][tx] = W[(size_t)(by * 32 + ty + j * 8) * NOUT + bx * 32 + tx];
    __syncthreads();
#pragma unroll
    for (int j = 0; j < 4; ++j)
      Wt[(size_t)(bx * 32 + ty + j * 8) * LDIM + by * 32 + tx] = f2bf(tile[tx][ty + j * 8]);
    return;
  }

  __shared__ double red[8];
  const int row = blockIdx.x;
  const int t = threadIdx.x;
  const float S = SQRT_HALF_F;

  const float4* xr = (const float4*)(x + (size_t)row * LDIM) + 4 * t;
  float v[16];
#pragma unroll
  for (int k = 0; k < 4; ++k) {
    float4 q = xr[k];
    v[4 * k] = q.x; v[4 * k + 1] = q.y; v[4 * k + 2] = q.z; v[4 * k + 3] = q.w;
  }

  double sa = 0.0, sq = 0.0;
  float a1[8], a2[4], a3[2], a4;
#pragma unroll
  for (int j = 0; j < 8; ++j) {
    float d = (v[2 * j] - v[2 * j + 1]) * S;
    a1[j] = (v[2 * j] + v[2 * j + 1]) * S;
    sa += (double)fabsf(d); sq += (double)d * (double)d;
  }
#pragma unroll
  for (int j = 0; j < 4; ++j) {
    float d = (a1[2 * j] - a1[2 * j + 1]) * S;
    a2[j] = (a1[2 * j] + a1[2 * j + 1]) * S;
    sa += (double)fabsf(d); sq += (double)d * (double)d;
  }
#pragma unroll
  for (int j = 0; j < 2; ++j) {
    float d = (a2[2 * j] - a2[2 * j + 1]) * S;
    a3[j] = (a2[2 * j] + a2[2 * j + 1]) * S;
    sa += (double)fabsf(d); sq += (double)d * (double)d;
  }
  {
    float d = (a3[0] - a3[1]) * S;
    a4 = (a3[0] + a3[1]) * S;
    sa += (double)fabsf(d); sq += (double)d * (double)d;
  }
  {
    float other = __shfl_xor(a4, 1, 64);
    if ((t & 1) == 0) {
      float d = (a4 - other) * S, ap = (a4 + other) * S;
      sa += (double)fabsf(d) + (double)fabsf(ap);
      sq += (double)d * (double)d + (double)ap * (double)ap;
    }
  }

  const int lane = t & 63, wid = t >> 6;
#pragma unroll
  for (int off = 32; off > 0; off >>= 1) {
    sa += __shfl_down(sa, off, 64);
    sq += __shfl_down(sq, off, 64);
  }
  if (lane == 0) { red[wid] = sa; red[4 + wid] = sq; }
  __syncthreads();
  if (t == 0) {
    partials[2 * (size_t)row + 0] = red[0] + red[1] + red[2] + red[3];
    partials[2 * (size_t)row + 1] = red[4] + red[5] + red[6] + red[7];
  }
}

// ---------------- Kernel 2: reduce partials -> threshold ----------------
__global__ __launch_bounds__(1024) void thr_kernel(const double* __restrict__ partials,
                                                   float* __restrict__ thr) {
  __shared__ double red[32];
  const int tid = threadIdx.x;
  double sa = 0.0, sq = 0.0;
#pragma unroll
  for (int k = 0; k < NROWS / 1024; ++k) {
    int i = tid + k * 1024;
    sa += partials[2 * i + 0];
    sq += partials[2 * i + 1];
  }
  const int lane = tid & 63, wid = tid >> 6;
#pragma unroll
  for (int off = 32; off > 0; off >>= 1) {
    sa += __shfl_down(sa, off, 64);
    sq += __shfl_down(sq, off, 64);
  }
  if (lane == 0) { red[wid] = sa; red[16 + wid] = sq; }
  __syncthreads();
  if (tid == 0) {
    double s = 0.0, q = 0.0;
#pragma unroll
    for (int i = 0; i < 16; ++i) { s += red[i]; q += red[16 + i]; }
    const double n = (double)NROWS * (double)LDIM;
    double mean = s / n;
    double var = (q - s * s / n) / (n - 1.0);
    *thr = (float)(mean + sqrt(var));
  }
}

// ---------------- Kernel 3: Haar recompute + mask + bf16 write ----------------
__global__ __launch_bounds__(256) void haar2_kernel(const float* __restrict__ x,
                                                    const float* __restrict__ thrp,
                                                    unsigned short* __restrict__ Am) {
  const float thr = *thrp;
  const int row = blockIdx.x;
  const int t = threadIdx.x;
  const float S = SQRT_HALF_F;

  const float4* xr = (const float4*)(x + (size_t)row * LDIM) + 4 * t;
  float v[16];
#pragma unroll
  for (int k = 0; k < 4; ++k) {
    float4 q = xr[k];
    v[4 * k] = q.x; v[4 * k + 1] = q.y; v[4 * k + 2] = q.z; v[4 * k + 3] = q.w;
  }

  unsigned short* orow = Am + (size_t)row * LDIM;
  float a1[8], a2[4], a3[2], a4;

  u16x8 d1;
#pragma unroll
  for (int j = 0; j < 8; ++j) {
    float d = (v[2 * j] - v[2 * j + 1]) * S;
    a1[j] = (v[2 * j] + v[2 * j + 1]) * S;
    d1[j] = mcvt(d, thr);
  }
  *(u16x8*)(orow + 2048 + 8 * t) = d1;

  u16x4 d2;
#pragma unroll
  for (int j = 0; j < 4; ++j) {
    float d = (a1[2 * j] - a1[2 * j + 1]) * S;
    a2[j] = (a1[2 * j] + a1[2 * j + 1]) * S;
    d2[j] = mcvt(d, thr);
  }
  *(u16x4*)(orow + 1024 + 4 * t) = d2;

  u16x2 d3;
#pragma unroll
  for (int j = 0; j < 2; ++j) {
    float d = (a2[2 * j] - a2[2 * j + 1]) * S;
    a3[j] = (a2[2 * j] + a2[2 * j + 1]) * S;
    d3[j] = mcvt(d, thr);
  }
  *(u16x2*)(orow + 512 + 2 * t) = d3;

  {
    float d = (a3[0] - a3[1]) * S;
    a4 = (a3[0] + a3[1]) * S;
    orow[256 + t] = mcvt(d, thr);
  }
  {
    float other = __shfl_xor(a4, 1, 64);
    if ((t & 1) == 0) {
      float d = (a4 - other) * S, ap = (a4 + other) * S;
      orow[128 + t / 2] = mcvt(d, thr);
      orow[t / 2] = mcvt(ap, thr);
    }
  }
}

// ---------------- Kernel 4: bf16 MFMA GEMM + ReLU, 512 threads ----------------
// C[8192x512] = relu( Am @ Wt^T ). Round-10 structure.
// Ledger: R1 (8w 32x32, 2blk/CU, 4w/SIMD, vmcnt(0) drain) gemm ~53us = 41us
// LDS-read wall + 12 overhead. R2/R5 (2 w/SIMD variants) both +12us: drain
// exposure needs 4 w/SIMD. LDS bytes depend ONLY on wave-tile shape:
// 32x32 -> 2.1 GB; 64x64 -> 1.07 GB (20.5us wall).
// This round: block 128m x 64n UNCHANGED (grid 512, 2 blk/CU, 8 waves,
// 4 w/SIMD) but waves pair up: 2 m-tiles of 64x64, each computed by 4 waves
// splitting BK=64 into four K=16 slots (32x32x16 MFMA, 2x2 frags). Per
// block-step: 32 ds_read_b128 + 32 MFMA (vs 64+64). Partial accumulators
// reduced through LDS once at the end (3 write/add rounds, ws-tree).
// Pipeline: 3-buffer staging + counted vmcnt(3) (T4): each wave's 3 loads
// for tile t+1 verified complete while t+2's 3 stay in flight -- no full
// drain in the main loop. LDS 72 KB -> still 2 blocks/CU (144 < 160).
// A-operand layout 32x32x16 (family-consistent w/ verified 16x16x32):
// row = lane&31, k = (lane>>5)*8 + e; B: col = lane&31, same k.
// C/D layout (guide-verified m74/m101): col = lane&31,
// row = (reg&3) + 8*(reg>>2) + 4*(lane>>5).
__global__ __launch_bounds__(512) void gemm_kernel(const unsigned short* __restrict__ Am,
                                                   const unsigned short* __restrict__ Wt,
                                                   float* __restrict__ out) {
  __shared__ __align__(16) unsigned short As[3][128 * 64];  // 48 KB
  __shared__ __align__(16) unsigned short Bs[3][64 * 64];   // 24 KB

  const int tid = threadIdx.x;
  const int lane = tid & 63, w = tid >> 6;      // 8 waves
  const int l31 = lane & 31, hi = lane >> 5;
  const int tm = w >> 2;                         // m-tile (0,1): rows tm*64..+64
  const int ws = w & 3;                          // K-slot within BK=64: k in [ws*16, ws*16+16)

  const int id = blockIdx.x;                    // grid 512
  const int xcd = id & 7, slot = id >> 3;
  const int nblk = slot & 7;
  const int mblk = (slot >> 3) * 8 + xcd;
  const int n0 = nblk * 64, m0 = mblk * 128;

  f32x16 acc[2][2] = {};   // frags (fi,fj): rows tm*64+fi*32, cols fj*32

  const int rl = lane >> 3;            // row within an 8-row DMA group
  const int cg = (lane & 7) ^ rl;      // XOR-swizzled source chunk index
  const unsigned short* AgBase = Am + (size_t)(m0 + rl) * LDIM + cg * 8;
  const unsigned short* BgBase = Wt + (size_t)(n0 + rl) * LDIM + cg * 8;

  // per-wave STAGE of one K-tile (3 async16): A 16 groups of 8 rows (2/wave),
  // B 8 groups (1/wave). Identical to R1.
#define GEMM_STAGE(buf, k0)                                                            \
  {                                                                                    \
    _Pragma("unroll")                                                                  \
    for (int j = 0; j < 2; ++j)                                                        \
      async16(&As[buf][(w * 2 + j) * 512], AgBase + (size_t)((w * 2 + j) * 8) * LDIM + (k0)); \
    async16(&Bs[buf][w * 512], BgBase + (size_t)(w * 8) * LDIM + (k0));                \
  }

  // per-wave COMPUTE of its K=16 slot: 2 A-frag reads + 2 B-frag reads + 4 MFMA.
  // Read addr: row*128B + chunk*16B, chunk = (ws*2 + hi) ^ (row & 7).
#define GEMM_COMPUTE(ASB, BSB)                                                        \
  {                                                                                   \
    short8 af[2], bfg[2];                                                             \
    _Pragma("unroll")                                                                 \
    for (int fi = 0; fi < 2; ++fi) {                                                  \
      const int arow = tm * 64 + fi * 32 + l31;                                       \
      af[fi] = *(const short8*)&(ASB)[arow * 64 + (((ws * 2 + hi) ^ (arow & 7)) * 8)]; \
    }                                                                                 \
    _Pragma("unroll")                                                                 \
    for (int fj = 0; fj < 2; ++fj) {                                                  \
      const int brow = fj * 32 + l31;                                                 \
      bfg[fj] = *(const short8*)&(BSB)[brow * 64 + (((ws * 2 + hi) ^ (brow & 7)) * 8)]; \
    }                                                                                 \
    _Pragma("unroll")                                                                 \
    for (int fi = 0; fi < 2; ++fi)                                                    \
      _Pragma("unroll")                                                               \
      for (int fj = 0; fj < 2; ++fj)                                                  \
        acc[fi][fj] = __builtin_amdgcn_mfma_f32_32x32x16_bf16(af[fi], bfg[fj],        \
                                                              acc[fi][fj], 0, 0, 0);  \
  }

  // prologue: stage tiles 0,1; wait for tile 0 (3 newest stay in flight)
  GEMM_STAGE(0, 0);
  GEMM_STAGE(1, 64);
  asm volatile("s_waitcnt vmcnt(3)" ::: "memory");
  __builtin_amdgcn_s_barrier();
  __builtin_amdgcn_sched_barrier(0);

  int ib0 = 0, ib1 = 1, ib2 = 2;
  for (int t = 0; t < (LDIM / 64) - 2; ++t) {
    GEMM_STAGE(ib2, (t + 2) * 64);       // tile t+2 issued; flies over compute
    GEMM_COMPUTE(As[ib0], Bs[ib0]);
    asm volatile("s_waitcnt vmcnt(3)" ::: "memory");   // tile t+1's 3 loads done
    __builtin_amdgcn_s_barrier();
    __builtin_amdgcn_sched_barrier(0);
    const int tmp = ib0; ib0 = ib1; ib1 = ib2; ib2 = tmp;
  }
  // t = 62: compute, then full drain for tile 63
  GEMM_COMPUTE(As[ib0], Bs[ib0]);
  asm volatile("s_waitcnt vmcnt(0)" ::: "memory");
  __builtin_amdgcn_s_barrier();
  __builtin_amdgcn_sched_barrier(0);
  // t = 63: final tile
  GEMM_COMPUTE(As[ib1], Bs[ib1]);
  __syncthreads();   // all reads done before scratch aliases As

  // ---- K-slot reduction: acc(ws=0) += acc(ws=1..3), tree via LDS scratch ----
  // Scratch: 2 tiles x 16 KB aliasing As. Layout per (tm, frag f, quad q):
  // f32x4 at sc + tm*4096 + f*1024 + q*256 + lane*4  (linear per wave, no conflicts)
  float* sc = (float*)&As[0][0];
#define SC_WRITE()                                                                    \
  { _Pragma("unroll")                                                                 \
    for (int fi = 0; fi < 2; ++fi)                                                    \
      _Pragma("unroll")                                                               \
      for (int fj = 0; fj < 2; ++fj)                                                  \
        _Pragma("unroll")                                                             \
        for (int q = 0; q < 4; ++q) {                                                 \
          f32x4 v;                                                                    \
          v[0] = acc[fi][fj][4 * q + 0]; v[1] = acc[fi][fj][4 * q + 1];               \
          v[2] = acc[fi][fj][4 * q + 2]; v[3] = acc[fi][fj][4 * q + 3];               \
          *(f32x4*)&sc[tm * 4096 + (fi * 2 + fj) * 1024 + q * 256 + lane * 4] = v;    \
        } }
#define SC_ADD()                                                                      \
  { _Pragma("unroll")                                                                 \
    for (int fi = 0; fi < 2; ++fi)                                                    \
      _Pragma("unroll")                                                               \
      for (int fj = 0; fj < 2; ++fj)                                                  \
        _Pragma("unroll")                                                             \
        for (int q = 0; q < 4; ++q) {                                                 \
          f32x4 v = *(const f32x4*)&sc[tm * 4096 + (fi * 2 + fj) * 1024 + q * 256 + lane * 4]; \
          acc[fi][fj][4 * q + 0] += v[0]; acc[fi][fj][4 * q + 1] += v[1];             \
          acc[fi][fj][4 * q + 2] += v[2]; acc[fi][fj][4 * q + 3] += v[3];             \
        } }

  if (ws == 1) SC_WRITE();
  __syncthreads();
  if (ws == 0) SC_ADD();
  __syncthreads();
  if (ws == 3) SC_WRITE();
  __syncthreads();
  if (ws == 2) SC_ADD();
  __syncthreads();
  if (ws == 2) SC_WRITE();
  __syncthreads();
  if (ws == 0) {
    SC_ADD();
    // C store: col = n0 + fj*32 + l31, row = m0 + tm*64 + fi*32 + 8q + 4hi + j
#pragma unroll
    for (int fi = 0; fi < 2; ++fi)
#pragma unroll
      for (int fj = 0; fj < 2; ++fj) {
        const int c = n0 + fj * 32 + l31;
#pragma unroll
        for (int q = 0; q < 4; ++q)
#pragma unroll
          for (int j = 0; j < 4; ++j) {
            const int r = m0 + tm * 64 + fi * 32 + 8 * q + 4 * hi + j;
            out[(size_t)r * NOUT + c] = fmaxf(acc[fi][fj][4 * q + j], 0.0f);
          }
      }
  }
}

extern "C" void kernel_launch(void* const* d_in, const int* in_sizes, int n_in,
                              void* d_out, int out_size, void* d_ws, size_t ws_size,
                              hipStream_t stream) {
  const float* x = (const float*)d_in[0];
  const float* W = (const float*)d_in[1];
  float* out = (float*)d_out;

  char* ws = (char*)d_ws;
  unsigned short* Am = (unsigned short*)(ws + AM_OFF);
  unsigned short* Wt = (unsigned short*)(ws + WT_OFF);
  double* partials = (double*)(ws + PART_OFF);
  float* thr = (float*)(ws + THR_OFF);

  haar1_kernel<<<NROWS + 2048, 256, 0, stream>>>(x, partials, W, Wt);
  thr_kernel<<<1, 1024, 0, stream>>>(partials, thr);
  haar2_kernel<<<NROWS, 256, 0, stream>>>(x, thr, Am);
  gemm_kernel<<<512, 512, 0, stream>>>(Am, Wt, out);
}

// Round 7
// 266.977 us; speedup vs baseline: 1.3291x; 1.0117x over previous
//
#include <hip/hip_runtime.h>
#include <hip/hip_bf16.h>
#include <math.h>

#define LDIM 4096
#define NROWS 8192
#define NOUT 512

static const float SQRT_HALF_F = 0.70710678118654752440f;

typedef __attribute__((ext_vector_type(8))) short short8;
typedef __attribute__((ext_vector_type(4))) float f32x4;
typedef __attribute__((ext_vector_type(8))) unsigned short u16x8;
typedef __attribute__((ext_vector_type(4))) unsigned short u16x4;
typedef __attribute__((ext_vector_type(2))) unsigned short u16x2;

// ws layout
#define AM_OFF   0ull                         // bf16 masked A: 8192*4096*2 = 67108864
#define WT_OFF   67108864ull                  // bf16 Wt (N x K): 512*4096*2 = 4194304
#define PART_OFF (WT_OFF + 4194304ull)        // double[8192*2] partials
#define THR_OFF  (PART_OFF + 131072ull)       // float[1]

__device__ inline unsigned short f2bf(float f) {
  union { float f; unsigned u; } v; v.f = f;
  unsigned r = (v.u + 0x7fffu + ((v.u >> 16) & 1u)) >> 16;
  return (unsigned short)r;
}

__device__ inline unsigned short mcvt(float f, float thr) {
  return f2bf((fabsf(f) > thr) ? f : 0.0f);
}

__device__ inline void async16(void* l, const void* g) {
  __builtin_amdgcn_global_load_lds((const __attribute__((address_space(1))) void*)g,
                                   (__attribute__((address_space(3))) void*)l, 16, 0, 0);
}

// ---------------- Kernel 1: Haar stats (blocks 0..8191) + W convert (tail) ----
__global__ __launch_bounds__(256) void haar1_kernel(const float* __restrict__ x,
                                                    double* __restrict__ partials,
                                                    const float* __restrict__ W,
                                                    unsigned short* __restrict__ Wt) {
  if (blockIdx.x >= NROWS) {
    // ---- fused wcvt: W (K x N fp32) -> Wt (N x K bf16) ----
    __shared__ float tile[32][33];
    const int wb = blockIdx.x - NROWS;
    const int bx = wb & 15;        // n tile (16)
    const int by = wb >> 4;        // k tile (128)
    const int tx = threadIdx.x & 31, ty = threadIdx.x >> 5;
#pragma unroll
    for (int j = 0; j < 4; ++j)
      tile[ty + j * 8][tx] = W[(size_t)(by * 32 + ty + j * 8) * NOUT + bx * 32 + tx];
    __syncthreads();
#pragma unroll
    for (int j = 0; j < 4; ++j)
      Wt[(size_t)(bx * 32 + ty + j * 8) * LDIM + by * 32 + tx] = f2bf(tile[tx][ty + j * 8]);
    return;
  }

  __shared__ double red[8];
  const int row = blockIdx.x;
  const int t = threadIdx.x;
  const float S = SQRT_HALF_F;

  const float4* xr = (const float4*)(x + (size_t)row * LDIM) + 4 * t;
  float v[16];
#pragma unroll
  for (int k = 0; k < 4; ++k) {
    float4 q = xr[k];
    v[4 * k] = q.x; v[4 * k + 1] = q.y; v[4 * k + 2] = q.z; v[4 * k + 3] = q.w;
  }

  double sa = 0.0, sq = 0.0;
  float a1[8], a2[4], a3[2], a4;
#pragma unroll
  for (int j = 0; j < 8; ++j) {
    float d = (v[2 * j] - v[2 * j + 1]) * S;
    a1[j] = (v[2 * j] + v[2 * j + 1]) * S;
    sa += (double)fabsf(d); sq += (double)d * (double)d;
  }
#pragma unroll
  for (int j = 0; j < 4; ++j) {
    float d = (a1[2 * j] - a1[2 * j + 1]) * S;
    a2[j] = (a1[2 * j] + a1[2 * j + 1]) * S;
    sa += (double)fabsf(d); sq += (double)d * (double)d;
  }
#pragma unroll
  for (int j = 0; j < 2; ++j) {
    float d = (a2[2 * j] - a2[2 * j + 1]) * S;
    a3[j] = (a2[2 * j] + a2[2 * j + 1]) * S;
    sa += (double)fabsf(d); sq += (double)d * (double)d;
  }
  {
    float d = (a3[0] - a3[1]) * S;
    a4 = (a3[0] + a3[1]) * S;
    sa += (double)fabsf(d); sq += (double)d * (double)d;
  }
  {
    float other = __shfl_xor(a4, 1, 64);
    if ((t & 1) == 0) {
      float d = (a4 - other) * S, ap = (a4 + other) * S;
      sa += (double)fabsf(d) + (double)fabsf(ap);
      sq += (double)d * (double)d + (double)ap * (double)ap;
    }
  }

  const int lane = t & 63, wid = t >> 6;
#pragma unroll
  for (int off = 32; off > 0; off >>= 1) {
    sa += __shfl_down(sa, off, 64);
    sq += __shfl_down(sq, off, 64);
  }
  if (lane == 0) { red[wid] = sa; red[4 + wid] = sq; }
  __syncthreads();
  if (t == 0) {
    partials[2 * (size_t)row + 0] = red[0] + red[1] + red[2] + red[3];
    partials[2 * (size_t)row + 1] = red[4] + red[5] + red[6] + red[7];
  }
}

// ---------------- Kernel 2: reduce partials -> threshold ----------------
__global__ __launch_bounds__(1024) void thr_kernel(const double* __restrict__ partials,
                                                   float* __restrict__ thr) {
  __shared__ double red[32];
  const int tid = threadIdx.x;
  double sa = 0.0, sq = 0.0;
#pragma unroll
  for (int k = 0; k < NROWS / 1024; ++k) {
    int i = tid + k * 1024;
    sa += partials[2 * i + 0];
    sq += partials[2 * i + 1];
  }
  const int lane = tid & 63, wid = tid >> 6;
#pragma unroll
  for (int off = 32; off > 0; off >>= 1) {
    sa += __shfl_down(sa, off, 64);
    sq += __shfl_down(sq, off, 64);
  }
  if (lane == 0) { red[wid] = sa; red[16 + wid] = sq; }
  __syncthreads();
  if (tid == 0) {
    double s = 0.0, q = 0.0;
#pragma unroll
    for (int i = 0; i < 16; ++i) { s += red[i]; q += red[16 + i]; }
    const double n = (double)NROWS * (double)LDIM;
    double mean = s / n;
    double var = (q - s * s / n) / (n - 1.0);
    *thr = (float)(mean + sqrt(var));
  }
}

// ---------------- Kernel 3: Haar recompute + mask + bf16 write ----------------
__global__ __launch_bounds__(256) void haar2_kernel(const float* __restrict__ x,
                                                    const float* __restrict__ thrp,
                                                    unsigned short* __restrict__ Am) {
  const float thr = *thrp;
  const int row = blockIdx.x;
  const int t = threadIdx.x;
  const float S = SQRT_HALF_F;

  const float4* xr = (const float4*)(x + (size_t)row * LDIM) + 4 * t;
  float v[16];
#pragma unroll
  for (int k = 0; k < 4; ++k) {
    float4 q = xr[k];
    v[4 * k] = q.x; v[4 * k + 1] = q.y; v[4 * k + 2] = q.z; v[4 * k + 3] = q.w;
  }

  unsigned short* orow = Am + (size_t)row * LDIM;
  float a1[8], a2[4], a3[2], a4;

  u16x8 d1;
#pragma unroll
  for (int j = 0; j < 8; ++j) {
    float d = (v[2 * j] - v[2 * j + 1]) * S;
    a1[j] = (v[2 * j] + v[2 * j + 1]) * S;
    d1[j] = mcvt(d, thr);
  }
  *(u16x8*)(orow + 2048 + 8 * t) = d1;

  u16x4 d2;
#pragma unroll
  for (int j = 0; j < 4; ++j) {
    float d = (a1[2 * j] - a1[2 * j + 1]) * S;
    a2[j] = (a1[2 * j] + a1[2 * j + 1]) * S;
    d2[j] = mcvt(d, thr);
  }
  *(u16x4*)(orow + 1024 + 4 * t) = d2;

  u16x2 d3;
#pragma unroll
  for (int j = 0; j < 2; ++j) {
    float d = (a2[2 * j] - a2[2 * j + 1]) * S;
    a3[j] = (a2[2 * j] + a2[2 * j + 1]) * S;
    d3[j] = mcvt(d, thr);
  }
  *(u16x2*)(orow + 512 + 2 * t) = d3;

  {
    float d = (a3[0] - a3[1]) * S;
    a4 = (a3[0] + a3[1]) * S;
    orow[256 + t] = mcvt(d, thr);
  }
  {
    float other = __shfl_xor(a4, 1, 64);
    if ((t & 1) == 0) {
      float d = (a4 - other) * S, ap = (a4 + other) * S;
      orow[128 + t / 2] = mcvt(d, thr);
      orow[t / 2] = mcvt(ap, thr);
    }
  }
}

// ---------------- Kernel 4: bf16 MFMA GEMM + ReLU, 512 threads ----------------
// C[8192x512] = relu( Am @ Wt^T ). Round-11 structure.
// Ledger: R1 (8w 32x32 waves, 2blk/CU, 4w/SIMD) gemm ~53us. R2/R5 (2w/SIMD)
// +12us: occupancy is sacred. R6 (K-split-4, 64x64 waves, f32x16 acc = 64
// VGPR acc) neutral -- almost certainly VGPR >128 halved occupancy and ate
// the LDS savings. This round: VGPR-SAFE LDS cut. Identical to R1 except
// wave mapping: 8 waves = 4 m-positions (tm) x 2 K-halves (kh) of BK=64.
// Each wave: 32m x 64n tile over its K=32 half, 16x16x32 MFMA, 2x4 frags
// (acc = 8 x f32x4 = 32 VGPR). Per wave-step: 6 ds_read_b128 + 8 MFMA
// (vs R1 8+8) -> block-step LDS 64->48 reads (-25%). 2-way K-half reduce
// through LDS scratch at the end (aliases As, +1 barrier, ~1us).
// Staging, dbuf-2, vmcnt(0)+s_barrier loop, XOR-8 swizzle: UNCHANGED from R1.
#define GEMM_COMPUTE(ASB, BSB)                                                        \
  {                                                                                   \
    short8 af[2], bf[4];                                                              \
    _Pragma("unroll")                                                                 \
    for (int mi = 0; mi < 2; ++mi) {                                                  \
      const int arow = tm * 32 + mi * 16 + l15;                                       \
      af[mi] = *(const short8*)&(ASB)[arow * 64 + (((kh * 4 + quad) ^ (arow & 7)) * 8)]; \
    }                                                                                 \
    _Pragma("unroll")                                                                 \
    for (int ni = 0; ni < 4; ++ni) {                                                  \
      const int brow = ni * 16 + l15;                                                 \
      bf[ni] = *(const short8*)&(BSB)[brow * 64 + (((kh * 4 + quad) ^ (brow & 7)) * 8)]; \
    }                                                                                 \
    _Pragma("unroll")                                                                 \
    for (int mi = 0; mi < 2; ++mi)                                                    \
      _Pragma("unroll")                                                               \
      for (int ni = 0; ni < 4; ++ni)                                                  \
        acc[mi][ni] = __builtin_amdgcn_mfma_f32_16x16x32_bf16(af[mi], bf[ni],         \
                                                              acc[mi][ni], 0, 0, 0);  \
  }

__global__ __launch_bounds__(512) void gemm_kernel(const unsigned short* __restrict__ Am,
                                                   const unsigned short* __restrict__ Wt,
                                                   float* __restrict__ out) {
  __shared__ __align__(16) unsigned short As[2][128 * 64];  // 2 x 16 KB
  __shared__ __align__(16) unsigned short Bs[2][64 * 64];   // 2 x  8 KB

  const int tid = threadIdx.x;
  const int lane = tid & 63, w = tid >> 6;      // 8 waves
  const int quad = lane >> 4, l15 = lane & 15;
  const int tm = w >> 1;                         // m-position: rows tm*32..+32
  const int kh = w & 1;                          // K-half of BK=64: k in [kh*32, kh*32+32)

  const int id = blockIdx.x;                    // grid 512
  const int xcd = id & 7, slot = id >> 3;
  const int nblk = slot & 7;
  const int mblk = (slot >> 3) * 8 + xcd;
  const int n0 = nblk * 64, m0 = mblk * 128;

  f32x4 acc[2][4] = {};   // wave tile 32m x 64n: frags (mi, ni)

  const int rl = lane >> 3;            // row within an 8-row DMA group
  const int cg = (lane & 7) ^ rl;      // XOR-swizzled source chunk index
  const unsigned short* AgBase = Am + (size_t)(m0 + rl) * LDIM + cg * 8;
  const unsigned short* BgBase = Wt + (size_t)(n0 + rl) * LDIM + cg * 8;

  // per-wave STAGE of one K-tile (identical to R1): A 16 groups of 8 rows
  // (2/wave), B 8 groups (1/wave). 3 async16 per wave per tile.
#define GEMM_STAGE(buf, k0)                                                            \
  {                                                                                    \
    _Pragma("unroll")                                                                  \
    for (int j = 0; j < 2; ++j)                                                        \
      async16(&As[buf][(w * 2 + j) * 512], AgBase + (size_t)((w * 2 + j) * 8) * LDIM + (k0)); \
    async16(&Bs[buf][w * 512], BgBase + (size_t)(w * 8) * LDIM + (k0));                \
  }

  // prologue: stage tile 0, wait, barrier
  GEMM_STAGE(0, 0);
  asm volatile("s_waitcnt vmcnt(0)" ::: "memory");
  __builtin_amdgcn_s_barrier();
  __builtin_amdgcn_sched_barrier(0);

  int cur = 0;
  for (int t = 0; t < (LDIM / 64) - 1; ++t) {
    GEMM_STAGE(cur ^ 1, (t + 1) * 64);   // next-tile prefetch flies over compute
    GEMM_COMPUTE(As[cur], Bs[cur]);
    asm volatile("s_waitcnt vmcnt(0)" ::: "memory");
    __builtin_amdgcn_s_barrier();
    __builtin_amdgcn_sched_barrier(0);
    cur ^= 1;
  }
  GEMM_COMPUTE(As[cur], Bs[cur]);        // epilogue tile, no prefetch
  __syncthreads();                       // all LDS reads done before scratch aliases As

  // ---- K-half reduction: kh=1 waves park partials in LDS, kh=0 adds+stores.
  // Scratch aliases As (32 KB): per tm-region 2048 floats (8 KB), layout
  // (mi*4+ni)*256 + lane*4 -> contiguous 1 KB per frag per wave, conflict-free.
  float* sc = (float*)&As[0][0];
  const int sbase = tm * 2048;
  if (kh == 1) {
#pragma unroll
    for (int mi = 0; mi < 2; ++mi)
#pragma unroll
      for (int ni = 0; ni < 4; ++ni)
        *(f32x4*)&sc[sbase + (mi * 4 + ni) * 256 + lane * 4] = acc[mi][ni];
  }
  __syncthreads();
  if (kh == 0) {
    // C/D layout (16x16): col = lane&15, row = quad*4 + reg (verified R1-R4)
#pragma unroll
    for (int mi = 0; mi < 2; ++mi)
#pragma unroll
      for (int ni = 0; ni < 4; ++ni) {
        f32x4 v = *(const f32x4*)&sc[sbase + (mi * 4 + ni) * 256 + lane * 4];
        acc[mi][ni] += v;
        const int r0 = m0 + tm * 32 + mi * 16 + quad * 4;
        const int c = n0 + ni * 16 + l15;
#pragma unroll
        for (int r = 0; r < 4; ++r)
          out[(size_t)(r0 + r) * NOUT + c] = fmaxf(acc[mi][ni][r], 0.0f);
      }
  }
}

extern "C" void kernel_launch(void* const* d_in, const int* in_sizes, int n_in,
                              void* d_out, int out_size, void* d_ws, size_t ws_size,
                              hipStream_t stream) {
  const float* x = (const float*)d_in[0];
  const float* W = (const float*)d_in[1];
  float* out = (float*)d_out;

  char* ws = (char*)d_ws;
  unsigned short* Am = (unsigned short*)(ws + AM_OFF);
  unsigned short* Wt = (unsigned short*)(ws + WT_OFF);
  double* partials = (double*)(ws + PART_OFF);
  float* thr = (float*)(ws + THR_OFF);

  haar1_kernel<<<NROWS + 2048, 256, 0, stream>>>(x, partials, W, Wt);
  thr_kernel<<<1, 1024, 0, stream>>>(partials, thr);
  haar2_kernel<<<NROWS, 256, 0, stream>>>(x, thr, Am);
  gemm_kernel<<<512, 512, 0, stream>>>(Am, Wt, out);
}